// Round 18
// baseline (176.170 us; speedup 1.0000x reference)
//
#include <hip/hip_runtime.h>
#include <hip/hip_bf16.h>

// ---- problem constants ----
#define BATCH 2
#define SEQ   2048
#define EMB   1024
#define NHEAD 16
#define HDIM  64
#define MTOT  (BATCH*SEQ)     // 4096
#define KTOT  EMB             // 1024

#define NX  (MTOT*EMB)        // 4,194,304  X elems
#define NW1 (3*EMB*EMB)       // 3,145,728  Wqkv elems
#define NW2 (EMB*EMB)         // 1,048,576  Wout elems
#define NCVT (NX+NW1+NW2)

typedef short bf8 __attribute__((ext_vector_type(8)));   // 8 bf16 (4 VGPRs) MFMA A/B frag
typedef short s4v __attribute__((ext_vector_type(4)));   // 4 bf16, 8B
typedef float f4  __attribute__((ext_vector_type(4)));   // MFMA C/D frag
typedef unsigned int uint;

__device__ __forceinline__ short f2b(float f) {
    __hip_bfloat16 h = __float2bfloat16(f);
    return __builtin_bit_cast(short, h);
}
// async global->LDS, 16B per lane; lds dest = wave-uniform base + lane*16
__device__ __forceinline__ void gl_lds16(const short* g, short* l) {
    __builtin_amdgcn_global_load_lds(
        (const __attribute__((address_space(1))) uint*)g,
        (__attribute__((address_space(3))) uint*)l, 16, 0, 0);
}
// 64B-row LDS tiles: bank swizzle (store global chunk c^f(r) at LDS chunk c).
// Invariant: valid when staging row-base and fragment row-base are both %16==0.
#define SWZ_SRC(lane)      ((((lane) ^ ((lane)>>2) ^ ((lane)>>4)) & 3) * 8)
#define SWZ_RD(quad, l16)  ((((quad) ^ (l16) ^ ((l16)>>2)) & 3) * 8)

// ============================================================================
// Kernel 0: fp32 -> bf16 convert (X, Wqkv, Wout). Coalesced float4 -> bf16x4.
// ============================================================================
__global__ __launch_bounds__(256) void cvt_all(
    const float* __restrict__ X, const float* __restrict__ W1,
    const float* __restrict__ W2,
    short* __restrict__ xb, short* __restrict__ w1b, short* __restrict__ w2b)
{
    int i4 = (blockIdx.x * 256 + threadIdx.x) * 4;
    const float* src; short* dst; int off;
    if (i4 < NX)            { src = X;  dst = xb;  off = i4; }
    else if (i4 < NX + NW1) { src = W1; dst = w1b; off = i4 - NX; }
    else                    { src = W2; dst = w2b; off = i4 - NX - NW1; }
    float4 v = *(const float4*)&src[off];
    s4v o; o[0]=f2b(v.x); o[1]=f2b(v.y); o[2]=f2b(v.z); o[3]=f2b(v.w);
    *(s4v*)&dst[off] = o;
}

// ============================================================================
// Kernel 1: QKV projection — FINAL == R23 (measured best, 3x reproduced:
// 43.4-43.8 µs, MfmaUtil 22, Occ 25). 128x128 tile, BK=64, 768 blocks =
// 3/CU, 32KB LDS, XCD region swizzle + half-K rolling pipeline:
//   stage(half h+1 -> region (h+1)&1); compute(region h&1); barrier
// Schedule-space fully measured: single-buf=45.1, THIS=43.8, 128x96@4/CU=52,
// 128x64=53, 2ph-256x192=56.8, 3-region-vmcnt4=60.7, dbuf-128^2@2/CU=64.4,
// 4ph-256^2=85.3. Only the zero-cost refinement paid.
// ============================================================================
__global__ __launch_bounds__(256) void gemm_qkv(
    const short* __restrict__ Xb, const short* __restrict__ Wb,
    const float* __restrict__ bias,
    short* __restrict__ qb, short* __restrict__ kb, short* __restrict__ vtb)
{
    __shared__ __align__(16) short As[2*128*32];   // 16KB [kc-region][row][32sh]
    __shared__ __align__(16) short Bs[2*128*32];   // 16KB
    const int tid  = threadIdx.x;
    const int lane = tid & 63;
    const int w    = tid >> 6;
    const int l16  = lane & 15, quad = lane >> 4;
    const int wm   = (w >> 1) * 64, wn = (w & 1) * 64;
    const int srow = (lane >> 2);
    const int scol = SWZ_SRC(lane);

    // XCD-chunked region swizzle (bijective over 768).
    const int id  = blockIdx.x;
    const int xcd = id & 7, k = id >> 3;            // k: 0..95
    const int rg  = k / 12, p = k - rg*12;          // rg: 0..7, p: 0..11
    const int R   = rg*8 + xcd;                     // 0..63
    const int bm  = (R & 7)*4 + (p & 3);            // 0..31  (M tile)
    const int bn  = (R >> 3)*3 + (p >> 2);          // 0..23  (N tile)

    // per-wave staging bases (row part is h-invariant)
    const size_t arow0 = (size_t)(bm*128 + w*32 +  0 + srow)*KTOT + scol;
    const size_t arow1 = (size_t)(bm*128 + w*32 + 16 + srow)*KTOT + scol;
    const size_t brow0 = (size_t)(bn*128 + w*32 +  0 + srow)*KTOT + scol;
    const size_t brow1 = (size_t)(bn*128 + w*32 + 16 + srow)*KTOT + scol;
    const int d0 = (w*32 +  0)*32;
    const int d1 = (w*32 + 16)*32;

    f4 acc[4][4] = {};

    // prologue: stage half 0 (kc=0, k0=0) -> region 0
    gl_lds16(&Xb[arow0], &As[d0]); gl_lds16(&Xb[arow1], &As[d1]);
    gl_lds16(&Wb[brow0], &Bs[d0]); gl_lds16(&Wb[brow1], &Bs[d1]);
    __syncthreads();

    #pragma unroll 2
    for (int h = 0; h < 32; h++) {
        const int reg = h & 1;
        if (h < 31) {
            const int hn  = h + 1;
            const int off = (hn >> 1)*64 + (hn & 1)*32;   // global k offset
            const int dr  = (hn & 1)*4096;                // LDS region
            gl_lds16(&Xb[arow0 + off], &As[dr + d0]);
            gl_lds16(&Xb[arow1 + off], &As[dr + d1]);
            gl_lds16(&Wb[brow0 + off], &Bs[dr + d0]);
            gl_lds16(&Wb[brow1 + off], &Bs[dr + d1]);
        }
        asm volatile("" ::: "memory");   // keep stage issue ahead of compute
        bf8 af[4], bf[4];
        #pragma unroll
        for (int t = 0; t < 4; t++) {
            af[t] = *(const bf8*)&As[reg*4096 + (wm + t*16 + l16)*32 + SWZ_RD(quad, l16)];
            bf[t] = *(const bf8*)&Bs[reg*4096 + (wn + t*16 + l16)*32 + SWZ_RD(quad, l16)];
        }
        #pragma unroll
        for (int mt = 0; mt < 4; mt++)
            #pragma unroll
            for (int nt = 0; nt < 4; nt++)
                acc[mt][nt] = __builtin_amdgcn_mfma_f32_16x16x32_bf16(af[mt], bf[nt], acc[mt][nt], 0, 0, 0);
        __syncthreads();   // drains stage(h+1) loads aged by the compute above
    }
    #pragma unroll
    for (int mt = 0; mt < 4; mt++)
    #pragma unroll
    for (int nt = 0; nt < 4; nt++) {
        int colg = bn*128 + wn + nt*16 + l16;
        float bv = bias[colg];
        #pragma unroll
        for (int r = 0; r < 4; r++) {
            int rowg = bm*128 + wm + mt*16 + quad*4 + r;
            short h = f2b(acc[mt][nt][r] + bv);
            int bb = rowg >> 11, s = rowg & 2047;
            if (colg < 1024) {
                int hh = colg >> 6, d = colg & 63;
                qb[(((bb*NHEAD + hh)*SEQ + s) << 6) + d] = h;
            } else if (colg < 2048) {
                int c2 = colg - 1024, hh = c2 >> 6, d = c2 & 63;
                kb[(((bb*NHEAD + hh)*SEQ + s) << 6) + d] = h;
            } else {
                int c3 = colg - 2048, hh = c3 >> 6, d = c3 & 63;
                int ssw = (s & ~63) | (((s & 15) << 2) | ((s >> 4) & 3));
                vtb[((bb*NHEAD + hh)*HDIM + d)*SEQ + ssw] = h;
            }
        }
    }
}

// ============================================================================
// Kernel 2: causal flash attention — R20 form (128-row Q tile, 512 blocks,
// XCD head-chunking: 4 heads/XCD = 2MB KV L2-resident).
// ============================================================================
__global__ __launch_bounds__(256, 3) void attn(
    const short* __restrict__ qb, const short* __restrict__ kb,
    const short* __restrict__ vtb, short* __restrict__ ctx)
{
    __shared__ __align__(16) short Ks[2*4096];      // 16KB [buf][c][key][32sh]
    __shared__ __align__(16) short Vs[2*4096];      // 16KB
    __shared__ __align__(16) short pl[4][32*64];    // 16KB (2 row-groups)
    const int tid = threadIdx.x;
    const int w = tid >> 6, lane = tid & 63;
    const int l16 = lane & 15, quad = lane >> 4;
    const int f  = blockIdx.x;                      // 0..511
    const int xcd = f & 7, j = f >> 3;              // j: 0..63
    const int bh  = xcd*4 + (j & 3);                // 4 heads per XCD
    const int slot = j >> 2;                        // 0..15
    const int s3 = slot & 7;
    const int hq = slot >> 3;                       // 0..1
    const int tq = hq ? (15 - s3) : s3;             // 0..15 (128-row Q tiles)
    const int q0w = tq*128 + w*16;                  // wave's rg0 base row
    const int base = bh * (SEQ*HDIM);
    short* myp = pl[w];
    const float SC = 0.125f * 1.44269504f;          // 1/sqrt(64) * log2(e)

    const int lq  = lane >> 2;
    const int lsw = SWZ_SRC(lane);

    const bool isk = (w < 2);
    short* tb = isk ? Ks : Vs;
    const int sstep = isk ? 64*HDIM : 64;
    const short* sp0; const short* sp1; const short* sp2; const short* sp3;
    int dof[4];
    {
        const int wb2 = (w & 1) * 4;
        #pragma unroll
        for (int tt = 0; tt < 4; tt++) {
            int t = wb2 + tt, cc = t & 1, g = (t >> 1) & 3;
            dof[tt] = (cc*64 + g*16)*32;
            const short* s = isk ? &kb[base + (g*16 + lq)*HDIM + cc*32 + lsw]
                                 : &vtb[base + (g*16 + lq)*SEQ + cc*32 + lsw];
            if (tt == 0) sp0 = s; else if (tt == 1) sp1 = s;
            else if (tt == 2) sp2 = s; else sp3 = s;
        }
    }

    bf8 qa[2][2];                                   // [rg][kc]
    #pragma unroll
    for (int rg = 0; rg < 2; rg++)
        #pragma unroll
        for (int kc = 0; kc < 2; kc++)
            qa[rg][kc] = *(const bf8*)&qb[base + (q0w + rg*64 + l16)*HDIM + kc*32 + quad*8];

    f4 oA[4] = {}, oB[4] = {};                      // rg0 / rg1 accumulators
    float lacc[2][4] = {};
    const int rdK = l16*32 + SWZ_RD(quad, l16);
    const int nst = 2*tq + 2;

    gl_lds16(sp0, tb + dof[0]); gl_lds16(sp1, tb + dof[1]);
    gl_lds16(sp2, tb + dof[2]); gl_lds16(sp3, tb + dof[3]);
    sp0 += sstep; sp1 += sstep; sp2 += sstep; sp3 += sstep;
    __syncthreads();

    int buf = 0;
    for (int st = 0; st < nst; st++) {
        if (st < nst - 1) {
            short* d = tb + (buf ^ 1)*4096;
            gl_lds16(sp0, d + dof[0]); gl_lds16(sp1, d + dof[1]);
            gl_lds16(sp2, d + dof[2]); gl_lds16(sp3, d + dof[3]);
            sp0 += sstep; sp1 += sstep; sp2 += sstep; sp3 += sstep;
        }
        const int kbase = buf*4096 + rdK;
        const bool rg0act = (st <= 2*tq);           // block-uniform
        // ---- QK^T + softmax + pack, per active row-group ----
        #pragma unroll
        for (int rg = 0; rg < 2; rg++) {
            if (rg == 0 && !rg0act) continue;
            f4 s[4] = {};
            #pragma unroll
            for (int kf = 0; kf < 4; kf++)
                #pragma unroll
                for (int c = 0; c < 2; c++) {
                    bf8 kfr = *(const bf8*)&Ks[kbase + (c*64 + kf*16)*32];
                    s[kf] = __builtin_amdgcn_mfma_f32_16x16x32_bf16(qa[rg][c], kfr, s[kf], 0, 0, 0);
                }
            const bool diag = (st == 2*tq + rg);    // block-uniform
            if (diag) {
                const int j0 = st*64;
                #pragma unroll
                for (int r = 0; r < 4; r++) {
                    const int row = quad*4 + r;
                    const int qi  = q0w + rg*64 + row;
                    float e[4];
                    #pragma unroll
                    for (int kf = 0; kf < 4; kf++) {
                        e[kf] = __builtin_amdgcn_exp2f(s[kf][r] * SC);
                        if (j0 + kf*16 + l16 > qi) e[kf] = 0.0f;
                        lacc[rg][r] += e[kf];
                    }
                    uint u01 = __builtin_amdgcn_perm(__builtin_bit_cast(uint, e[1]),
                                                     __builtin_bit_cast(uint, e[0]), 0x07060302u);
                    uint u23 = __builtin_amdgcn_perm(__builtin_bit_cast(uint, e[3]),
                                                     __builtin_bit_cast(uint, e[2]), 0x07060302u);
                    uint2 pk = {u01, u23};
                    int c8 = ((l16 >> 1) ^ (row & 7));
                    *(uint2*)&myp[(rg*16 + row)*64 + c8*8 + (l16 & 1)*4] = pk;
                }
            } else {
                #pragma unroll
                for (int r = 0; r < 4; r++) {
                    const int row = quad*4 + r;
                    float e[4];
                    #pragma unroll
                    for (int kf = 0; kf < 4; kf++) {
                        e[kf] = __builtin_amdgcn_exp2f(s[kf][r] * SC);
                        lacc[rg][r] += e[kf];
                    }
                    uint u01 = __builtin_amdgcn_perm(__builtin_bit_cast(uint, e[1]),
                                                     __builtin_bit_cast(uint, e[0]), 0x07060302u);
                    uint u23 = __builtin_amdgcn_perm(__builtin_bit_cast(uint, e[3]),
                                                     __builtin_bit_cast(uint, e[2]), 0x07060302u);
                    uint2 pk = {u01, u23};
                    int c8 = ((l16 >> 1) ^ (row & 7));
                    *(uint2*)&myp[(rg*16 + row)*64 + c8*8 + (l16 & 1)*4] = pk;
                }
            }
        }
        asm volatile("" ::: "memory");
        // ---- PV, per active row-group ----
        if (rg0act) {
            bf8 pa[2];
            #pragma unroll
            for (int kc = 0; kc < 2; kc++)
                pa[kc] = *(const bf8*)&myp[l16*64 + (((kc*4 + quad) ^ (l16 & 7)))*8];
            #pragma unroll
            for (int dt = 0; dt < 4; dt++)
                #pragma unroll
                for (int c = 0; c < 2; c++) {
                    bf8 vf = *(const bf8*)&Vs[kbase + (c*64 + dt*16)*32];
                    oA[dt] = __builtin_amdgcn_mfma_f32_16x16x32_bf16(pa[c], vf, oA[dt], 0, 0, 0);
                }
        }
        {
            bf8 pa[2];
            #pragma unroll
            for (int kc = 0; kc < 2; kc++)
                pa[kc] = *(const bf8*)&myp[(16 + l16)*64 + (((kc*4 + quad) ^ (l16 & 7)))*8];
            #pragma unroll
            for (int dt = 0; dt < 4; dt++)
                #pragma unroll
                for (int c = 0; c < 2; c++) {
                    bf8 vf = *(const bf8*)&Vs[kbase + (c*64 + dt*16)*32];
                    oB[dt] = __builtin_amdgcn_mfma_f32_16x16x32_bf16(pa[c], vf, oB[dt], 0, 0, 0);
                }
        }
        __syncthreads();
        buf ^= 1;
    }
    #pragma unroll
    for (int rg = 0; rg < 2; rg++)
        #pragma unroll
        for (int r = 0; r < 4; r++) {
            float v = lacc[rg][r];
            v += __shfl_xor(v, 1);
            v += __shfl_xor(v, 2);
            v += __shfl_xor(v, 4);
            v += __shfl_xor(v, 8);
            lacc[rg][r] = v;
        }
    const int b = bh >> 4, h = bh & 15;
    #pragma unroll
    for (int rg = 0; rg < 2; rg++)
        #pragma unroll
        for (int r = 0; r < 4; r++) {
            float inv = 1.0f / lacc[rg][r];
            int qi = q0w + rg*64 + quad*4 + r;
            int rowoff = (b*SEQ + qi)*EMB + h*HDIM;
            #pragma unroll
            for (int dt = 0; dt < 4; dt++)
                ctx[rowoff + dt*16 + l16] = f2b((rg ? oB[dt][r] : oA[dt][r]) * inv);
        }
}

// ============================================================================
// Kernel 3: output projection — R27: R18 geometry (128x64 tile, BK=64, grid
// 512 = 2/CU, XCD swizzle) + the R23 half-K rolling pipeline (zero-cost:
// same LDS, same barriers-per-K, loads age one half-compute phase before
// the drain). Identical transformation to the one that gave qkv -3%.
// ============================================================================
__global__ __launch_bounds__(256) void gemm_out(
    const short* __restrict__ A, const short* __restrict__ Wb,
    const float* __restrict__ bias, float* __restrict__ out)
{
    __shared__ __align__(16) short As[2*128*32];   // 16KB [kc-region][row][32sh]
    __shared__ __align__(16) short Bs[2*64*32];    //  8KB [kc-region][row][32sh]
    const int f = blockIdx.x;                      // 0..511
    // bijective: xcd&3 = bm>>3, j&7 = bm&7; xcd>>2 = bn>>3, j>>3 = bn&7
    const int xcd = f & 7, j = f >> 3;             // j: 0..63
    const int bm  = (xcd & 3)*8 + (j & 7);         // 0..31 (M tile, 128 rows)
    const int bn  = (xcd >> 2)*8 + (j >> 3);       // 0..15 (N tile, 64 cols)
    const int tid  = threadIdx.x;
    const int lane = tid & 63;
    const int w    = tid >> 6;
    const int l16  = lane & 15, quad = lane >> 4;
    const int wm   = (w >> 1) * 64, wn = (w & 1) * 32;
    const int srow = (lane >> 2);
    const int scol = SWZ_SRC(lane);
    const int swz  = SWZ_RD(quad, l16);

    // per-wave staging bases (row part h-invariant):
    // A: 8 chunks/half over 4 waves x 2 (g = w*2+t); B: 4 chunks/half (g = w)
    const size_t arow0 = (size_t)(bm*128 + (w*2+0)*16 + srow)*KTOT + scol;
    const size_t arow1 = (size_t)(bm*128 + (w*2+1)*16 + srow)*KTOT + scol;
    const size_t brow  = (size_t)(bn*64  + w*16       + srow)*KTOT + scol;
    const int da0 = ((w*2+0)*16)*32;
    const int da1 = ((w*2+1)*16)*32;
    const int db  = (w*16)*32;

    f4 acc[4][2] = {};

    // prologue: stage half 0 -> region 0
    gl_lds16(&A[arow0], &As[da0]); gl_lds16(&A[arow1], &As[da1]);
    gl_lds16(&Wb[brow], &Bs[db]);
    __syncthreads();

    #pragma unroll 2
    for (int h = 0; h < 32; h++) {
        const int reg = h & 1;
        if (h < 31) {
            const int hn  = h + 1;
            const int off = (hn >> 1)*64 + (hn & 1)*32;   // global k offset
            gl_lds16(&A[arow0 + off], &As[(hn & 1)*4096 + da0]);
            gl_lds16(&A[arow1 + off], &As[(hn & 1)*4096 + da1]);
            gl_lds16(&Wb[brow + off], &Bs[(hn & 1)*2048 + db]);
        }
        asm volatile("" ::: "memory");   // keep stage issue ahead of compute
        bf8 af[4], bf[2];
        #pragma unroll
        for (int t = 0; t < 4; t++)
            af[t] = *(const bf8*)&As[reg*4096 + (wm + t*16 + l16)*32 + swz];
        #pragma unroll
        for (int t = 0; t < 2; t++)
            bf[t] = *(const bf8*)&Bs[reg*2048 + (wn + t*16 + l16)*32 + swz];
        #pragma unroll
        for (int mt = 0; mt < 4; mt++)
            #pragma unroll
            for (int nt = 0; nt < 2; nt++)
                acc[mt][nt] = __builtin_amdgcn_mfma_f32_16x16x32_bf16(af[mt], bf[nt], acc[mt][nt], 0, 0, 0);
        __syncthreads();   // drains stage(h+1) loads aged by the compute above
    }

    #pragma unroll
    for (int mt = 0; mt < 4; mt++)
    #pragma unroll
    for (int nt = 0; nt < 2; nt++) {
        int colg = bn*64 + wn + nt*16 + l16;
        float bv = bias[colg];
        #pragma unroll
        for (int r = 0; r < 4; r++) {
            int rowg = bm*128 + wm + mt*16 + quad*4 + r;
            out[(size_t)rowg*EMB + colg] = acc[mt][nt][r] + bv;
        }
    }
}

extern "C" void kernel_launch(void* const* d_in, const int* in_sizes, int n_in,
                              void* d_out, int out_size, void* d_ws, size_t ws_size,
                              hipStream_t stream) {
    const float* X    = (const float*)d_in[0];   // [B,S,E] fp32
    const float* Wqkv = (const float*)d_in[1];   // [3E,E]  fp32
    const float* Bqkv = (const float*)d_in[2];   // [3E]    fp32
    const float* Wout = (const float*)d_in[3];   // [E,E]   fp32
    const float* Bout = (const float*)d_in[4];   // [E]     fp32
    float* out = (float*)d_out;                  // [B,S,E] fp32

    short* xb    = (short*)d_ws;                 // bf16 X      (8 MB)
    short* w1b   = xb  + NX;                     // bf16 Wqkv   (6 MB)
    short* w2b   = w1b + NW1;                    // bf16 Wout   (2 MB)
    short* qb    = w2b + NW2;
    short* kb    = qb  + NX;
    short* vtb   = kb  + NX;
    short* ctx   = vtb + NX;                     // total 48 MB

    cvt_all<<<NCVT/1024, 256, 0, stream>>>(X, Wqkv, Wout, xb, w1b, w2b);
    gemm_qkv<<<dim3(768), 256, 0, stream>>>(xb, w1b, Bqkv, qb, kb, vtb);
    attn<<<dim3(512), 256, 0, stream>>>(qb, kb, vtb, ctx);
    gemm_out<<<dim3(512), 256, 0, stream>>>(ctx, w2b, Bout, out);
}

// Round 20
// 172.499 us; speedup vs baseline: 1.0213x; 1.0213x over previous
//
#include <hip/hip_runtime.h>
#include <hip/hip_bf16.h>

// ---- problem constants ----
#define BATCH 2
#define SEQ   2048
#define EMB   1024
#define NHEAD 16
#define HDIM  64
#define MTOT  (BATCH*SEQ)     // 4096
#define KTOT  EMB             // 1024

#define NX  (MTOT*EMB)        // 4,194,304  X elems
#define NW1 (3*EMB*EMB)       // 3,145,728  Wqkv elems
#define NW2 (EMB*EMB)         // 1,048,576  Wout elems
#define NCVT (NX+NW1+NW2)

typedef short bf8 __attribute__((ext_vector_type(8)));   // 8 bf16 (4 VGPRs) MFMA A/B frag
typedef short s4v __attribute__((ext_vector_type(4)));   // 4 bf16, 8B
typedef float f4  __attribute__((ext_vector_type(4)));   // MFMA C/D frag
typedef unsigned int uint;

__device__ __forceinline__ short f2b(float f) {
    __hip_bfloat16 h = __float2bfloat16(f);
    return __builtin_bit_cast(short, h);
}
// async global->LDS, 16B per lane; lds dest = wave-uniform base + lane*16
__device__ __forceinline__ void gl_lds16(const short* g, short* l) {
    __builtin_amdgcn_global_load_lds(
        (const __attribute__((address_space(1))) uint*)g,
        (__attribute__((address_space(3))) uint*)l, 16, 0, 0);
}
// 64B-row LDS tiles: bank swizzle (store global chunk c^f(r) at LDS chunk c).
// Invariant: valid when staging row-base and fragment row-base are both %16==0.
#define SWZ_SRC(lane)      ((((lane) ^ ((lane)>>2) ^ ((lane)>>4)) & 3) * 8)
#define SWZ_RD(quad, l16)  ((((quad) ^ (l16) ^ ((l16)>>2)) & 3) * 8)

// ============================================================================
// Kernel 0: fp32 -> bf16 convert (X, Wqkv, Wout). Coalesced float4 -> bf16x4.
// ============================================================================
__global__ __launch_bounds__(256) void cvt_all(
    const float* __restrict__ X, const float* __restrict__ W1,
    const float* __restrict__ W2,
    short* __restrict__ xb, short* __restrict__ w1b, short* __restrict__ w2b)
{
    int i4 = (blockIdx.x * 256 + threadIdx.x) * 4;
    const float* src; short* dst; int off;
    if (i4 < NX)            { src = X;  dst = xb;  off = i4; }
    else if (i4 < NX + NW1) { src = W1; dst = w1b; off = i4 - NX; }
    else                    { src = W2; dst = w2b; off = i4 - NX - NW1; }
    float4 v = *(const float4*)&src[off];
    s4v o; o[0]=f2b(v.x); o[1]=f2b(v.y); o[2]=f2b(v.z); o[3]=f2b(v.w);
    *(s4v*)&dst[off] = o;
}

// ============================================================================
// Kernel 1: QKV projection — FINAL == R23 (measured best, 4x reproduced:
// 43.4-43.9 µs, MfmaUtil 22, Occ 25). 128x128 tile, BK=64, 768 blocks =
// 3/CU, 32KB LDS, XCD region swizzle + half-K rolling pipeline:
//   stage(half h+1 -> region (h+1)&1); compute(region h&1); barrier
// Schedule-space fully measured: single-buf=45.1, THIS=43.8, 128x96@4/CU=52,
// 128x64=53, 2ph-256x192=56.8, 3-region-vmcnt4=60.7, dbuf-128^2@2/CU=64.4,
// 4ph-256^2=85.3. Only the zero-cost refinement paid.
// ============================================================================
__global__ __launch_bounds__(256) void gemm_qkv(
    const short* __restrict__ Xb, const short* __restrict__ Wb,
    const float* __restrict__ bias,
    short* __restrict__ qb, short* __restrict__ kb, short* __restrict__ vtb)
{
    __shared__ __align__(16) short As[2*128*32];   // 16KB [kc-region][row][32sh]
    __shared__ __align__(16) short Bs[2*128*32];   // 16KB
    const int tid  = threadIdx.x;
    const int lane = tid & 63;
    const int w    = tid >> 6;
    const int l16  = lane & 15, quad = lane >> 4;
    const int wm   = (w >> 1) * 64, wn = (w & 1) * 64;
    const int srow = (lane >> 2);
    const int scol = SWZ_SRC(lane);

    // XCD-chunked region swizzle (bijective over 768).
    const int id  = blockIdx.x;
    const int xcd = id & 7, k = id >> 3;            // k: 0..95
    const int rg  = k / 12, p = k - rg*12;          // rg: 0..7, p: 0..11
    const int R   = rg*8 + xcd;                     // 0..63
    const int bm  = (R & 7)*4 + (p & 3);            // 0..31  (M tile)
    const int bn  = (R >> 3)*3 + (p >> 2);          // 0..23  (N tile)

    // per-wave staging bases (row part is h-invariant)
    const size_t arow0 = (size_t)(bm*128 + w*32 +  0 + srow)*KTOT + scol;
    const size_t arow1 = (size_t)(bm*128 + w*32 + 16 + srow)*KTOT + scol;
    const size_t brow0 = (size_t)(bn*128 + w*32 +  0 + srow)*KTOT + scol;
    const size_t brow1 = (size_t)(bn*128 + w*32 + 16 + srow)*KTOT + scol;
    const int d0 = (w*32 +  0)*32;
    const int d1 = (w*32 + 16)*32;

    f4 acc[4][4] = {};

    // prologue: stage half 0 (kc=0, k0=0) -> region 0
    gl_lds16(&Xb[arow0], &As[d0]); gl_lds16(&Xb[arow1], &As[d1]);
    gl_lds16(&Wb[brow0], &Bs[d0]); gl_lds16(&Wb[brow1], &Bs[d1]);
    __syncthreads();

    #pragma unroll 2
    for (int h = 0; h < 32; h++) {
        const int reg = h & 1;
        if (h < 31) {
            const int hn  = h + 1;
            const int off = (hn >> 1)*64 + (hn & 1)*32;   // global k offset
            const int dr  = (hn & 1)*4096;                // LDS region
            gl_lds16(&Xb[arow0 + off], &As[dr + d0]);
            gl_lds16(&Xb[arow1 + off], &As[dr + d1]);
            gl_lds16(&Wb[brow0 + off], &Bs[dr + d0]);
            gl_lds16(&Wb[brow1 + off], &Bs[dr + d1]);
        }
        asm volatile("" ::: "memory");   // keep stage issue ahead of compute
        bf8 af[4], bf[4];
        #pragma unroll
        for (int t = 0; t < 4; t++) {
            af[t] = *(const bf8*)&As[reg*4096 + (wm + t*16 + l16)*32 + SWZ_RD(quad, l16)];
            bf[t] = *(const bf8*)&Bs[reg*4096 + (wn + t*16 + l16)*32 + SWZ_RD(quad, l16)];
        }
        #pragma unroll
        for (int mt = 0; mt < 4; mt++)
            #pragma unroll
            for (int nt = 0; nt < 4; nt++)
                acc[mt][nt] = __builtin_amdgcn_mfma_f32_16x16x32_bf16(af[mt], bf[nt], acc[mt][nt], 0, 0, 0);
        __syncthreads();   // drains stage(h+1) loads aged by the compute above
    }
    #pragma unroll
    for (int mt = 0; mt < 4; mt++)
    #pragma unroll
    for (int nt = 0; nt < 4; nt++) {
        int colg = bn*128 + wn + nt*16 + l16;
        float bv = bias[colg];
        #pragma unroll
        for (int r = 0; r < 4; r++) {
            int rowg = bm*128 + wm + mt*16 + quad*4 + r;
            short h = f2b(acc[mt][nt][r] + bv);
            int bb = rowg >> 11, s = rowg & 2047;
            if (colg < 1024) {
                int hh = colg >> 6, d = colg & 63;
                qb[(((bb*NHEAD + hh)*SEQ + s) << 6) + d] = h;
            } else if (colg < 2048) {
                int c2 = colg - 1024, hh = c2 >> 6, d = c2 & 63;
                kb[(((bb*NHEAD + hh)*SEQ + s) << 6) + d] = h;
            } else {
                int c3 = colg - 2048, hh = c3 >> 6, d = c3 & 63;
                int ssw = (s & ~63) | (((s & 15) << 2) | ((s >> 4) & 3));
                vtb[((bb*NHEAD + hh)*HDIM + d)*SEQ + ssw] = h;
            }
        }
    }
}

// ============================================================================
// Kernel 2: causal flash attention — R20 form (128-row Q tile, 512 blocks,
// XCD head-chunking: 4 heads/XCD = 2MB KV L2-resident).
// ============================================================================
__global__ __launch_bounds__(256, 3) void attn(
    const short* __restrict__ qb, const short* __restrict__ kb,
    const short* __restrict__ vtb, short* __restrict__ ctx)
{
    __shared__ __align__(16) short Ks[2*4096];      // 16KB [buf][c][key][32sh]
    __shared__ __align__(16) short Vs[2*4096];      // 16KB
    __shared__ __align__(16) short pl[4][32*64];    // 16KB (2 row-groups)
    const int tid = threadIdx.x;
    const int w = tid >> 6, lane = tid & 63;
    const int l16 = lane & 15, quad = lane >> 4;
    const int f  = blockIdx.x;                      // 0..511
    const int xcd = f & 7, j = f >> 3;              // j: 0..63
    const int bh  = xcd*4 + (j & 3);                // 4 heads per XCD
    const int slot = j >> 2;                        // 0..15
    const int s3 = slot & 7;
    const int hq = slot >> 3;                       // 0..1
    const int tq = hq ? (15 - s3) : s3;             // 0..15 (128-row Q tiles)
    const int q0w = tq*128 + w*16;                  // wave's rg0 base row
    const int base = bh * (SEQ*HDIM);
    short* myp = pl[w];
    const float SC = 0.125f * 1.44269504f;          // 1/sqrt(64) * log2(e)

    const int lq  = lane >> 2;
    const int lsw = SWZ_SRC(lane);

    const bool isk = (w < 2);
    short* tb = isk ? Ks : Vs;
    const int sstep = isk ? 64*HDIM : 64;
    const short* sp0; const short* sp1; const short* sp2; const short* sp3;
    int dof[4];
    {
        const int wb2 = (w & 1) * 4;
        #pragma unroll
        for (int tt = 0; tt < 4; tt++) {
            int t = wb2 + tt, cc = t & 1, g = (t >> 1) & 3;
            dof[tt] = (cc*64 + g*16)*32;
            const short* s = isk ? &kb[base + (g*16 + lq)*HDIM + cc*32 + lsw]
                                 : &vtb[base + (g*16 + lq)*SEQ + cc*32 + lsw];
            if (tt == 0) sp0 = s; else if (tt == 1) sp1 = s;
            else if (tt == 2) sp2 = s; else sp3 = s;
        }
    }

    bf8 qa[2][2];                                   // [rg][kc]
    #pragma unroll
    for (int rg = 0; rg < 2; rg++)
        #pragma unroll
        for (int kc = 0; kc < 2; kc++)
            qa[rg][kc] = *(const bf8*)&qb[base + (q0w + rg*64 + l16)*HDIM + kc*32 + quad*8];

    f4 oA[4] = {}, oB[4] = {};                      // rg0 / rg1 accumulators
    float lacc[2][4] = {};
    const int rdK = l16*32 + SWZ_RD(quad, l16);
    const int nst = 2*tq + 2;

    gl_lds16(sp0, tb + dof[0]); gl_lds16(sp1, tb + dof[1]);
    gl_lds16(sp2, tb + dof[2]); gl_lds16(sp3, tb + dof[3]);
    sp0 += sstep; sp1 += sstep; sp2 += sstep; sp3 += sstep;
    __syncthreads();

    int buf = 0;
    for (int st = 0; st < nst; st++) {
        if (st < nst - 1) {
            short* d = tb + (buf ^ 1)*4096;
            gl_lds16(sp0, d + dof[0]); gl_lds16(sp1, d + dof[1]);
            gl_lds16(sp2, d + dof[2]); gl_lds16(sp3, d + dof[3]);
            sp0 += sstep; sp1 += sstep; sp2 += sstep; sp3 += sstep;
        }
        const int kbase = buf*4096 + rdK;
        const bool rg0act = (st <= 2*tq);           // block-uniform
        // ---- QK^T + softmax + pack, per active row-group ----
        #pragma unroll
        for (int rg = 0; rg < 2; rg++) {
            if (rg == 0 && !rg0act) continue;
            f4 s[4] = {};
            #pragma unroll
            for (int kf = 0; kf < 4; kf++)
                #pragma unroll
                for (int c = 0; c < 2; c++) {
                    bf8 kfr = *(const bf8*)&Ks[kbase + (c*64 + kf*16)*32];
                    s[kf] = __builtin_amdgcn_mfma_f32_16x16x32_bf16(qa[rg][c], kfr, s[kf], 0, 0, 0);
                }
            const bool diag = (st == 2*tq + rg);    // block-uniform
            if (diag) {
                const int j0 = st*64;
                #pragma unroll
                for (int r = 0; r < 4; r++) {
                    const int row = quad*4 + r;
                    const int qi  = q0w + rg*64 + row;
                    float e[4];
                    #pragma unroll
                    for (int kf = 0; kf < 4; kf++) {
                        e[kf] = __builtin_amdgcn_exp2f(s[kf][r] * SC);
                        if (j0 + kf*16 + l16 > qi) e[kf] = 0.0f;
                        lacc[rg][r] += e[kf];
                    }
                    uint u01 = __builtin_amdgcn_perm(__builtin_bit_cast(uint, e[1]),
                                                     __builtin_bit_cast(uint, e[0]), 0x07060302u);
                    uint u23 = __builtin_amdgcn_perm(__builtin_bit_cast(uint, e[3]),
                                                     __builtin_bit_cast(uint, e[2]), 0x07060302u);
                    uint2 pk = {u01, u23};
                    int c8 = ((l16 >> 1) ^ (row & 7));
                    *(uint2*)&myp[(rg*16 + row)*64 + c8*8 + (l16 & 1)*4] = pk;
                }
            } else {
                #pragma unroll
                for (int r = 0; r < 4; r++) {
                    const int row = quad*4 + r;
                    float e[4];
                    #pragma unroll
                    for (int kf = 0; kf < 4; kf++) {
                        e[kf] = __builtin_amdgcn_exp2f(s[kf][r] * SC);
                        lacc[rg][r] += e[kf];
                    }
                    uint u01 = __builtin_amdgcn_perm(__builtin_bit_cast(uint, e[1]),
                                                     __builtin_bit_cast(uint, e[0]), 0x07060302u);
                    uint u23 = __builtin_amdgcn_perm(__builtin_bit_cast(uint, e[3]),
                                                     __builtin_bit_cast(uint, e[2]), 0x07060302u);
                    uint2 pk = {u01, u23};
                    int c8 = ((l16 >> 1) ^ (row & 7));
                    *(uint2*)&myp[(rg*16 + row)*64 + c8*8 + (l16 & 1)*4] = pk;
                }
            }
        }
        asm volatile("" ::: "memory");
        // ---- PV, per active row-group ----
        if (rg0act) {
            bf8 pa[2];
            #pragma unroll
            for (int kc = 0; kc < 2; kc++)
                pa[kc] = *(const bf8*)&myp[l16*64 + (((kc*4 + quad) ^ (l16 & 7)))*8];
            #pragma unroll
            for (int dt = 0; dt < 4; dt++)
                #pragma unroll
                for (int c = 0; c < 2; c++) {
                    bf8 vf = *(const bf8*)&Vs[kbase + (c*64 + dt*16)*32];
                    oA[dt] = __builtin_amdgcn_mfma_f32_16x16x32_bf16(pa[c], vf, oA[dt], 0, 0, 0);
                }
        }
        {
            bf8 pa[2];
            #pragma unroll
            for (int kc = 0; kc < 2; kc++)
                pa[kc] = *(const bf8*)&myp[(16 + l16)*64 + (((kc*4 + quad) ^ (l16 & 7)))*8];
            #pragma unroll
            for (int dt = 0; dt < 4; dt++)
                #pragma unroll
                for (int c = 0; c < 2; c++) {
                    bf8 vf = *(const bf8*)&Vs[kbase + (c*64 + dt*16)*32];
                    oB[dt] = __builtin_amdgcn_mfma_f32_16x16x32_bf16(pa[c], vf, oB[dt], 0, 0, 0);
                }
        }
        __syncthreads();
        buf ^= 1;
    }
    #pragma unroll
    for (int rg = 0; rg < 2; rg++)
        #pragma unroll
        for (int r = 0; r < 4; r++) {
            float v = lacc[rg][r];
            v += __shfl_xor(v, 1);
            v += __shfl_xor(v, 2);
            v += __shfl_xor(v, 4);
            v += __shfl_xor(v, 8);
            lacc[rg][r] = v;
        }
    const int b = bh >> 4, h = bh & 15;
    #pragma unroll
    for (int rg = 0; rg < 2; rg++)
        #pragma unroll
        for (int r = 0; r < 4; r++) {
            float inv = 1.0f / lacc[rg][r];
            int qi = q0w + rg*64 + quad*4 + r;
            int rowoff = (b*SEQ + qi)*EMB + h*HDIM;
            #pragma unroll
            for (int dt = 0; dt < 4; dt++)
                ctx[rowoff + dt*16 + l16] = f2b((rg ? oB[dt][r] : oA[dt][r]) * inv);
        }
}

// ============================================================================
// Kernel 3: output projection — FINAL == R18 plain form (the variant in the
// session's two best totals, 173.3/174.6). 128x64 tile, BK=64, grid 512 =
// 2/CU, 16:6 MFMA:stage density, XCD swizzle.
// ============================================================================
__global__ __launch_bounds__(256) void gemm_out(
    const short* __restrict__ A, const short* __restrict__ Wb,
    const float* __restrict__ bias, float* __restrict__ out)
{
    __shared__ __align__(16) short As[2*128*32];   // 16KB [kc][row][32sh]
    __shared__ __align__(16) short Bs[2*64*32];    //  8KB [kc][row][32sh]
    const int f = blockIdx.x;                      // 0..511
    // bijective: xcd&3 = bm>>3, j&7 = bm&7; xcd>>2 = bn>>3, j>>3 = bn&7
    const int xcd = f & 7, j = f >> 3;             // j: 0..63
    const int bm  = (xcd & 3)*8 + (j & 7);         // 0..31 (M tile, 128 rows)
    const int bn  = (xcd >> 2)*8 + (j >> 3);       // 0..15 (N tile, 64 cols)
    const int tid  = threadIdx.x;
    const int lane = tid & 63;
    const int w    = tid >> 6;
    const int l16  = lane & 15, quad = lane >> 4;
    const int wm   = (w >> 1) * 64, wn = (w & 1) * 32;
    const int srow = (lane >> 2);
    const int scol = SWZ_SRC(lane);
    f4 acc[4][2] = {};
    for (int k0 = 0; k0 < KTOT; k0 += 64) {
        // A: 16 chunks (8 row-groups x 2 kc) over 4 waves x 4
        #pragma unroll
        for (int t = 0; t < 4; t++) {
            const int a  = w*4 + t;                 // 0..15
            const int kc = a & 1, g = a >> 1;       // g: 0..7
            int ra = bm*128 + g*16 + srow;
            gl_lds16(&A[(size_t)ra*KTOT + k0 + kc*32 + scol], &As[kc*4096 + g*16*32]);
        }
        // B: 8 chunks (4 row-groups x 2 kc) over 4 waves x 2
        #pragma unroll
        for (int t = 0; t < 2; t++) {
            const int b  = w*2 + t;                 // 0..7
            const int kc = b & 1, g = b >> 1;       // g: 0..3
            int rb = bn*64 + g*16 + srow;
            gl_lds16(&Wb[(size_t)rb*KTOT + k0 + kc*32 + scol], &Bs[kc*2048 + g*16*32]);
        }
        __syncthreads();
        #pragma unroll
        for (int kc = 0; kc < 2; kc++) {
            bf8 af[4], bf[2];
            #pragma unroll
            for (int t = 0; t < 4; t++)
                af[t] = *(const bf8*)&As[kc*4096 + (wm + t*16 + l16)*32 + SWZ_RD(quad, l16)];
            #pragma unroll
            for (int t = 0; t < 2; t++)
                bf[t] = *(const bf8*)&Bs[kc*2048 + (wn + t*16 + l16)*32 + SWZ_RD(quad, l16)];
            #pragma unroll
            for (int mt = 0; mt < 4; mt++)
                #pragma unroll
                for (int nt = 0; nt < 2; nt++)
                    acc[mt][nt] = __builtin_amdgcn_mfma_f32_16x16x32_bf16(af[mt], bf[nt], acc[mt][nt], 0, 0, 0);
        }
        __syncthreads();
    }
    #pragma unroll
    for (int mt = 0; mt < 4; mt++)
    #pragma unroll
    for (int nt = 0; nt < 2; nt++) {
        int colg = bn*64 + wn + nt*16 + l16;
        float bv = bias[colg];
        #pragma unroll
        for (int r = 0; r < 4; r++) {
            int rowg = bm*128 + wm + mt*16 + quad*4 + r;
            out[(size_t)rowg*EMB + colg] = acc[mt][nt][r] + bv;
        }
    }
}

extern "C" void kernel_launch(void* const* d_in, const int* in_sizes, int n_in,
                              void* d_out, int out_size, void* d_ws, size_t ws_size,
                              hipStream_t stream) {
    const float* X    = (const float*)d_in[0];   // [B,S,E] fp32
    const float* Wqkv = (const float*)d_in[1];   // [3E,E]  fp32
    const float* Bqkv = (const float*)d_in[2];   // [3E]    fp32
    const float* Wout = (const float*)d_in[3];   // [E,E]   fp32
    const float* Bout = (const float*)d_in[4];   // [E]     fp32
    float* out = (float*)d_out;                  // [B,S,E] fp32

    short* xb    = (short*)d_ws;                 // bf16 X      (8 MB)
    short* w1b   = xb  + NX;                     // bf16 Wqkv   (6 MB)
    short* w2b   = w1b + NW1;                    // bf16 Wout   (2 MB)
    short* qb    = w2b + NW2;
    short* kb    = qb  + NX;
    short* vtb   = kb  + NX;
    short* ctx   = vtb + NX;                     // total 48 MB

    cvt_all<<<NCVT/1024, 256, 0, stream>>>(X, Wqkv, Wout, xb, w1b, w2b);
    gemm_qkv<<<dim3(768), 256, 0, stream>>>(xb, w1b, Bqkv, qb, kb, vtb);
    attn<<<dim3(512), 256, 0, stream>>>(qb, kb, vtb, ctx);
    gemm_out<<<dim3(512), 256, 0, stream>>>(ctx, w2b, Bout, out);
}